// Round 12
// baseline (272.011 us; speedup 1.0000x reference)
//
#include <hip/hip_runtime.h>
#include <math.h>

#define NN 50000
#define EE 1600000
#define DD 128
#define NB 391           // buckets of 128 nodes
#define SLAB 5120        // slab capacity per bucket (mean 4096, +16 sigma)
#define MROWS 32
#define MGRID 1563       // (NN + MROWS - 1) / MROWS
#define BTILE 4096       // k_bin tile

typedef __attribute__((ext_vector_type(8))) short short8v;
typedef __attribute__((ext_vector_type(4))) float f32x4;
typedef __attribute__((ext_vector_type(2))) float floatx2;

// workspace layout (bytes)
#define HVB_OFF     0            // [NN*128] fp8 = 6,400,000
#define CTXB_OFF    6400000      // [NN*128] bf16 = 12,800,000
#define BIN_OFF     19200000     // [NB*SLAB] u32 = 8,007,680 (dead after k_bsort)
#define PBN_OFF     19200000     //   overlay: [MGRID*128] f32 = 800,256
#define PBQ_OFF     20000256     //   overlay: [MGRID*128] f32 = 800,256
#define SRCS_OFF    27207680     // [NB*SLAB] u16 = 4,003,840
#define LD_OFF      31211520     // [NN] f32
#define LS_OFF      31411520     // [NN] f32
#define START_OFF   31611520     // [NN] i32
#define CNTN_OFF    31811520     // [NN] i32
#define W1T_OFF     32011520     // [128*256] bf16
#define W2T_OFF     32077056     // [128*128] bf16
#define WPT_OFF     32109824     // [128*128] bf16
#define BKC_OFF     32142592     // [512] i32 (zeroed)
#define MEAN_OFF    32144640     // [128] f32
#define ISTD_OFF    32145152     // [128] f32  (ends 32,145,664)
#define ZERO_OFF    BKC_OFF
#define ZERO_LEN    2048         // BKC only

__device__ __forceinline__ unsigned short f2bf(float f) {
  union { float f; unsigned u; } v; v.f = f;
  unsigned r = v.u + 0x7FFFu + ((v.u >> 16) & 1u);   // round-to-nearest-even
  return (unsigned short)(r >> 16);
}

// ---------------------------------------------------------------- prep: weight transposes (to [n][k] bf16)
__global__ __launch_bounds__(256) void k_prep_w(const float* __restrict__ w1,
    const float* __restrict__ w2, const float* __restrict__ wp,
    unsigned short* __restrict__ w1t, unsigned short* __restrict__ w2t,
    unsigned short* __restrict__ wpt) {
  int t = blockIdx.x * 256 + threadIdx.x;            // 0..65535
  if (t < 32768) {
    int n = t & 127, k = t >> 7;                     // k 0..255
    w1t[n * 256 + k] = f2bf(w1[(size_t)k * 128 + n]);
  } else if (t < 49152) {
    int i = t - 32768; int n = i & 127, k = i >> 7;
    w2t[n * 128 + k] = f2bf(w2[(size_t)k * 128 + n]);
  } else {
    int i = t - 49152; int n = i & 127, k = i >> 7;
    wpt[n * 128 + k] = f2bf(wp[(size_t)k * 128 + n]);
  }
}

// ---------------------------------------------------------------- hv (fp8) + ld/ls, fused  [MFMA]
__global__ __launch_bounds__(256) void k_hv2(const float* __restrict__ nf,
    const unsigned short* __restrict__ wpt, const float* __restrict__ bp,
    const float* __restrict__ wed, const float* __restrict__ wes,
    float* __restrict__ ld, float* __restrict__ ls,
    unsigned char* __restrict__ hvb) {
  __shared__ unsigned short xs[64][136];
  int tid = threadIdx.x;
  int m0 = blockIdx.x * 64;
  int c4 = tid & 31;
  float4 wdv = *(const float4*)(wed + c4 * 4);
  float4 wsv = *(const float4*)(wes + c4 * 4);
  #pragma unroll
  for (int e = 0; e < 8; ++e) {
    int idx = tid + 256 * e;                         // float4 index, 2048 total
    int row = idx >> 5;
    int m = m0 + row;
    int mc = (m < NN) ? m : (NN - 1);
    float4 v = *(const float4*)(nf + (size_t)mc * 128 + c4 * 4);
    ushort4 bb;
    bb.x = f2bf(v.x); bb.y = f2bf(v.y); bb.z = f2bf(v.z); bb.w = f2bf(v.w);
    *(ushort4*)&xs[row][c4 * 4] = bb;
    float pa = v.x * wdv.x + v.y * wdv.y + v.z * wdv.z + v.w * wdv.w;
    float pb = v.x * wsv.x + v.y * wsv.y + v.z * wsv.z + v.w * wsv.w;
    #pragma unroll
    for (int o = 16; o; o >>= 1) { pa += __shfl_xor(pa, o); pb += __shfl_xor(pb, o); }
    if (c4 == 0 && m < NN) { ld[m] = pa; ls[m] = pb; }
  }
  __syncthreads();
  int wid = tid >> 6, lane = tid & 63;
  int wm = wid >> 1, wn = wid & 1;
  int l15 = lane & 15, lg = lane >> 4;
  f32x4 acc[4][2];                                   // [n-frag][m-frag]
  #pragma unroll
  for (int nf2 = 0; nf2 < 4; ++nf2)
    #pragma unroll
    for (int mf = 0; mf < 2; ++mf) acc[nf2][mf] = (f32x4){0.f, 0.f, 0.f, 0.f};
  for (int ks = 0; ks < 4; ++ks) {
    short8v aw[4], bx[2];
    #pragma unroll
    for (int nf2 = 0; nf2 < 4; ++nf2) {
      int n = wn * 64 + nf2 * 16 + l15;
      aw[nf2] = *(const short8v*)(wpt + (size_t)n * 128 + ks * 32 + lg * 8);
    }
    #pragma unroll
    for (int mf = 0; mf < 2; ++mf)
      bx[mf] = *(const short8v*)&xs[wm * 32 + mf * 16 + l15][ks * 32 + lg * 8];
    #pragma unroll
    for (int nf2 = 0; nf2 < 4; ++nf2)
      #pragma unroll
      for (int mf = 0; mf < 2; ++mf)
        acc[nf2][mf] = __builtin_amdgcn_mfma_f32_16x16x32_bf16(aw[nf2], bx[mf], acc[nf2][mf], 0, 0, 0);
  }
  #pragma unroll
  for (int nf2 = 0; nf2 < 4; ++nf2) {
    float4 bp4 = *(const float4*)(bp + wn * 64 + nf2 * 16 + lg * 4);
    #pragma unroll
    for (int mf = 0; mf < 2; ++mf) {
      int m = m0 + wm * 32 + mf * 16 + l15;
      if (m < NN) {
        int w = __builtin_amdgcn_cvt_pk_fp8_f32(acc[nf2][mf][0] + bp4.x,
                                                acc[nf2][mf][1] + bp4.y, 0, false);
        w = __builtin_amdgcn_cvt_pk_fp8_f32(acc[nf2][mf][2] + bp4.z,
                                            acc[nf2][mf][3] + bp4.w, w, true);
        *(int*)(hvb + (size_t)m * 128 + wn * 64 + nf2 * 16 + lg * 4) = w;
      }
    }
  }
}

// ---------------------------------------------------------------- sort S1: bin edges (packed dst<<16|src) into bucket slabs
__global__ __launch_bounds__(256) void k_bin(const int* __restrict__ src,
    const int* __restrict__ dst, int* __restrict__ bkc,
    unsigned* __restrict__ bin) {
  __shared__ unsigned slot[BTILE];
  __shared__ int hist[512], sc[512], loff[512], lcur[512], gbase[512];
  int tid = threadIdx.x;
  int tbase = blockIdx.x * BTILE;
  int tlen = min(BTILE, EE - tbase);
  unsigned pk[BTILE / 256];
  for (int i = tid; i < 512; i += 256) hist[i] = 0;
  __syncthreads();
  #pragma unroll
  for (int k = 0; k < BTILE / 256; ++k) {
    int i = k * 256 + tid;
    if (i < tlen) {
      int e = tbase + i;
      pk[k] = ((unsigned)dst[e] << 16) | (unsigned)src[e];
      atomicAdd(&hist[pk[k] >> 23], 1);
    }
  }
  __syncthreads();
  for (int i = tid; i < 512; i += 256) sc[i] = hist[i];
  __syncthreads();
  for (int off = 1; off < 512; off <<= 1) {
    int v0 = sc[tid] + ((tid >= off) ? sc[tid - off] : 0);
    int i1 = tid + 256;
    int v1 = sc[i1] + ((i1 >= off) ? sc[i1 - off] : 0);
    __syncthreads();
    sc[tid] = v0; sc[i1] = v1;
    __syncthreads();
  }
  for (int i = tid; i < 512; i += 256) { loff[i] = sc[i] - hist[i]; lcur[i] = sc[i] - hist[i]; }
  __syncthreads();
  #pragma unroll
  for (int k = 0; k < BTILE / 256; ++k) {
    int i = k * 256 + tid;
    if (i < tlen) {
      int r = atomicAdd(&lcur[pk[k] >> 23], 1);
      slot[r] = pk[k];
    }
  }
  __syncthreads();
  for (int i = tid; i < 512; i += 256) gbase[i] = hist[i] ? atomicAdd(&bkc[i], hist[i]) : 0;
  __syncthreads();
  #pragma unroll
  for (int k = 0; k < BTILE / 256; ++k) {
    int i = k * 256 + tid;
    if (i < tlen) {
      unsigned p = slot[i];
      int b = p >> 23;
      bin[(size_t)b * SLAB + gbase[b] + (i - loff[b])] = p;
    }
  }
}

// ---------------------------------------------------------------- sort S2: per-bucket node sort (128 nodes/bucket)
__global__ __launch_bounds__(256) void k_bsort(const unsigned* __restrict__ bin,
    const int* __restrict__ bkc, unsigned short* __restrict__ srcs,
    int* __restrict__ start, int* __restrict__ cntn) {
  __shared__ unsigned short outL[SLAB];
  __shared__ int hist[128], scA[128], cur[128];
  int tid = threadIdx.x;
  int b = blockIdx.x;
  size_t base = (size_t)b * SLAB;
  int cnt = bkc[b];
  int node0 = b << 7;
  int nnb = min(128, NN - node0);
  if (tid < 128) hist[tid] = 0;
  __syncthreads();
  for (int i = tid; i < cnt; i += 256)
    atomicAdd(&hist[(bin[base + i] >> 16) & 127], 1);
  __syncthreads();
  if (tid < 128) scA[tid] = hist[tid];
  __syncthreads();
  for (int off = 1; off < 128; off <<= 1) {
    int v = 0;
    if (tid < 128) v = scA[tid] + ((tid >= off) ? scA[tid - off] : 0);
    __syncthreads();
    if (tid < 128) scA[tid] = v;
    __syncthreads();
  }
  if (tid < 128) {
    int ex = scA[tid] - hist[tid];
    cur[tid] = ex;
    if (tid < nnb) { start[node0 + tid] = (int)base + ex; cntn[node0 + tid] = hist[tid]; }
  }
  __syncthreads();
  for (int i = tid; i < cnt; i += 256) {
    unsigned p = bin[base + i];
    int r = atomicAdd(&cur[(p >> 16) & 127], 1);
    outL[r] = (unsigned short)(p & 0xFFFFu);
  }
  __syncthreads();
  for (int i = tid; i < cnt; i += 256) srcs[base + i] = outL[i];
}

// ---------------------------------------------------------------- edge softmax + aggregate + ELU -> bf16 context
// one wave per node; e8 = lane&7 (edge slot), sl = lane>>3 (feature slice):
// tail butterfly over xor 1/2/4 (DPP-friendly); epilogue: 16 lanes x uint4 store
__global__ __launch_bounds__(256) void k_agg(const unsigned char* __restrict__ hvb,
    const float* __restrict__ ld, const float* __restrict__ ls,
    const float* __restrict__ be_p, const int* __restrict__ start,
    const int* __restrict__ cntn, const unsigned short* __restrict__ srcs,
    unsigned short* __restrict__ ctxb) {
  int wid = (blockIdx.x * 256 + threadIdx.x) >> 6;
  int lane = threadIdx.x & 63;
  if (wid >= NN) return;
  int cnt = cntn[wid];
  int e8 = lane & 7, sl = lane >> 3;
  floatx2 acc2[8];
  #pragma unroll
  for (int i = 0; i < 8; ++i) acc2[i] = (floatx2){0.f, 0.f};
  float rfin = 1.f;
  if (cnt > 0) {
    int s = start[wid];
    float base = ld[wid] + be_p[0];
    if (cnt <= 64) {
      float lg = -INFINITY;
      unsigned adr = 0;
      if (lane < cnt) {
        int sv = srcs[s + lane];
        adr = (unsigned)sv << 7;
        float l = base + ls[sv];
        lg = (l >= 0.f) ? l : 0.01f * l;
      }
      float mx = lg;
      #pragma unroll
      for (int o = 32; o; o >>= 1) mx = fmaxf(mx, __shfl_xor(mx, o));
      float ev = (lane < cnt) ? __expf(lg - mx) : 0.f;
      float dsum = ev;
      #pragma unroll
      for (int o = 32; o; o >>= 1) dsum += __shfl_xor(dsum, o);
      ev *= 1.f / dsum;                              // pre-normalize: no post-divide
      int nit = (cnt + 7) >> 3;
      #pragma unroll 2
      for (int j8 = 0; j8 < nit; ++j8) {
        int jj = (j8 << 3) + e8;
        float evj = __shfl(ev, jj);
        unsigned aj = (unsigned)__shfl((int)adr, jj);
        uint4 U = *(const uint4*)(hvb + aj + sl * 16);
        floatx2 ev2 = (floatx2){evj, evj};
        acc2[0] += ev2 * __builtin_amdgcn_cvt_pk_f32_fp8((int)U.x, false);
        acc2[1] += ev2 * __builtin_amdgcn_cvt_pk_f32_fp8((int)U.x, true);
        acc2[2] += ev2 * __builtin_amdgcn_cvt_pk_f32_fp8((int)U.y, false);
        acc2[3] += ev2 * __builtin_amdgcn_cvt_pk_f32_fp8((int)U.y, true);
        acc2[4] += ev2 * __builtin_amdgcn_cvt_pk_f32_fp8((int)U.z, false);
        acc2[5] += ev2 * __builtin_amdgcn_cvt_pk_f32_fp8((int)U.z, true);
        acc2[6] += ev2 * __builtin_amdgcn_cvt_pk_f32_fp8((int)U.w, false);
        acc2[7] += ev2 * __builtin_amdgcn_cvt_pk_f32_fp8((int)U.w, true);
      }
    } else {
      // fallback: online softmax (cnt > 64; statistically ~never at this size)
      float m = -INFINITY, dsum = 0.f;
      for (int c0 = 0; c0 < cnt; c0 += 64) {
        int len = min(64, cnt - c0);
        float lg = -INFINITY;
        unsigned adr = 0;
        if (lane < len) {
          int sv = srcs[s + c0 + lane];
          adr = (unsigned)sv << 7;
          float l = base + ls[sv];
          lg = (l >= 0.f) ? l : 0.01f * l;
        }
        float cm = lg;
        #pragma unroll
        for (int o = 32; o; o >>= 1) cm = fmaxf(cm, __shfl_xor(cm, o));
        float nm = fmaxf(m, cm);
        float sc = __expf(m - nm);
        floatx2 sc2 = (floatx2){sc, sc};
        #pragma unroll
        for (int i = 0; i < 8; ++i) acc2[i] *= sc2;
        dsum *= sc;
        float ev = (lane < len) ? __expf(lg - nm) : 0.f;
        dsum += ev;
        int nit = (len + 7) >> 3;
        for (int j8 = 0; j8 < nit; ++j8) {
          int jj = (j8 << 3) + e8;
          float evj = __shfl(ev, jj);
          unsigned aj = (unsigned)__shfl((int)adr, jj);
          uint4 U = *(const uint4*)(hvb + aj + sl * 16);
          floatx2 ev2 = (floatx2){evj, evj};
          acc2[0] += ev2 * __builtin_amdgcn_cvt_pk_f32_fp8((int)U.x, false);
          acc2[1] += ev2 * __builtin_amdgcn_cvt_pk_f32_fp8((int)U.x, true);
          acc2[2] += ev2 * __builtin_amdgcn_cvt_pk_f32_fp8((int)U.y, false);
          acc2[3] += ev2 * __builtin_amdgcn_cvt_pk_f32_fp8((int)U.y, true);
          acc2[4] += ev2 * __builtin_amdgcn_cvt_pk_f32_fp8((int)U.z, false);
          acc2[5] += ev2 * __builtin_amdgcn_cvt_pk_f32_fp8((int)U.z, true);
          acc2[6] += ev2 * __builtin_amdgcn_cvt_pk_f32_fp8((int)U.w, false);
          acc2[7] += ev2 * __builtin_amdgcn_cvt_pk_f32_fp8((int)U.w, true);
        }
        m = nm;
      }
      #pragma unroll
      for (int o = 32; o; o >>= 1) dsum += __shfl_xor(dsum, o);
      rfin = 1.f / dsum;
    }
  }
  // reduce across the 8 edge-slots: xor 1,2 are quad_perm (VALU-speed DPP), xor 4 swizzle
  #pragma unroll
  for (int o = 1; o <= 4; o <<= 1)
    #pragma unroll
    for (int i = 0; i < 8; ++i) {
      acc2[i].x += __shfl_xor(acc2[i].x, o);
      acc2[i].y += __shfl_xor(acc2[i].y, o);
    }
  // epilogue: lanes with (lane&7)<2 each ELU+pack 8 features -> one uint4 store
  int h = lane & 7;
  if (h < 2) {
    float v[8];
    #pragma unroll
    for (int q = 0; q < 4; ++q) {
      floatx2 a = acc2[h * 4 + q];
      v[2 * q] = a.x * rfin;
      v[2 * q + 1] = a.y * rfin;
    }
    #pragma unroll
    for (int q = 0; q < 8; ++q)
      v[q] = (v[q] > 0.f) ? v[q] : (__expf(v[q]) - 1.f);   // ELU via fast exp
    uint4 u;
    u.x = (unsigned)f2bf(v[0]) | ((unsigned)f2bf(v[1]) << 16);
    u.y = (unsigned)f2bf(v[2]) | ((unsigned)f2bf(v[3]) << 16);
    u.z = (unsigned)f2bf(v[4]) | ((unsigned)f2bf(v[5]) << 16);
    u.w = (unsigned)f2bf(v[6]) | ((unsigned)f2bf(v[7]) << 16);
    *(uint4*)(ctxb + (size_t)wid * 128 + sl * 16 + h * 8) = u;
  }
}

// ---------------------------------------------------------------- fused MLP [MFMA], 32-row tiles, no global atomics
__global__ __launch_bounds__(256) void k_mlp2(const unsigned short* __restrict__ ctxb,
    const float* __restrict__ nf,
    const unsigned short* __restrict__ w1t, const float* __restrict__ b1,
    const unsigned short* __restrict__ w2t, const float* __restrict__ b2,
    float* __restrict__ out, float* __restrict__ pbn, float* __restrict__ pbq) {
  __shared__ unsigned short xs[MROWS][264];          // [m][k] bf16 (ctx | nf)
  __shared__ unsigned short h1s[MROWS][136];         // [m][n] bf16
  __shared__ float bns[128], bnq[128];
  int tid = threadIdx.x;
  int m0 = blockIdx.x * MROWS;
  if (tid < 128) { bns[tid] = 0.f; bnq[tid] = 0.f; }
  #pragma unroll
  for (int e = 0; e < 2; ++e) {
    int idx = tid + 256 * e;
    int row = idx >> 4, c8 = idx & 15;
    int m = m0 + row; if (m >= NN) m = NN - 1;
    uint4 v = *(const uint4*)(ctxb + (size_t)m * 128 + c8 * 8);
    *(uint4*)&xs[row][c8 * 8] = v;
  }
  #pragma unroll
  for (int e = 0; e < 4; ++e) {
    int idx = tid + 256 * e;
    int row = idx >> 5, c4 = idx & 31;
    int m = m0 + row; if (m >= NN) m = NN - 1;
    float4 w = *(const float4*)(nf + (size_t)m * 128 + c4 * 4);
    ushort4 cc;
    cc.x = f2bf(w.x); cc.y = f2bf(w.y); cc.z = f2bf(w.z); cc.w = f2bf(w.w);
    *(ushort4*)&xs[row][128 + c4 * 4] = cc;
  }
  __syncthreads();
  int wid = tid >> 6, lane = tid & 63;
  int wm = wid >> 1, wn = wid & 1;                   // wave tile: 16 rows x 64 cols
  int l15 = lane & 15, lg = lane >> 4;
  f32x4 acc[4];
  #pragma unroll
  for (int nf2 = 0; nf2 < 4; ++nf2) acc[nf2] = (f32x4){0.f, 0.f, 0.f, 0.f};
  for (int ks = 0; ks < 8; ++ks) {
    short8v a = *(const short8v*)&xs[wm * 16 + l15][ks * 32 + lg * 8];
    #pragma unroll
    for (int nf2 = 0; nf2 < 4; ++nf2) {
      int n = wn * 64 + nf2 * 16 + l15;
      short8v b = *(const short8v*)(w1t + (size_t)n * 256 + ks * 32 + lg * 8);
      acc[nf2] = __builtin_amdgcn_mfma_f32_16x16x32_bf16(a, b, acc[nf2], 0, 0, 0);
    }
  }
  {
    float b1n[4];
    #pragma unroll
    for (int nf2 = 0; nf2 < 4; ++nf2) b1n[nf2] = b1[wn * 64 + nf2 * 16 + l15];
    #pragma unroll
    for (int nf2 = 0; nf2 < 4; ++nf2)
      #pragma unroll
      for (int r = 0; r < 4; ++r) {
        int row = wm * 16 + lg * 4 + r;
        int col = wn * 64 + nf2 * 16 + l15;
        h1s[row][col] = f2bf(fmaxf(acc[nf2][r] + b1n[nf2], 0.f));
      }
  }
  __syncthreads();
  f32x4 acc2[4];
  #pragma unroll
  for (int nf2 = 0; nf2 < 4; ++nf2) acc2[nf2] = (f32x4){0.f, 0.f, 0.f, 0.f};
  for (int ks = 0; ks < 4; ++ks) {
    short8v bh = *(const short8v*)&h1s[wm * 16 + l15][ks * 32 + lg * 8];
    #pragma unroll
    for (int nf2 = 0; nf2 < 4; ++nf2) {
      int n = wn * 64 + nf2 * 16 + l15;
      short8v aw = *(const short8v*)(w2t + (size_t)n * 128 + ks * 32 + lg * 8);
      acc2[nf2] = __builtin_amdgcn_mfma_f32_16x16x32_bf16(aw, bh, acc2[nf2], 0, 0, 0);
    }
  }
  {
    int m = m0 + wm * 16 + l15;
    bool valid = (m < NN);
    float hs[4][4], hq[4][4];
    #pragma unroll
    for (int nf2 = 0; nf2 < 4; ++nf2) {
      int f0 = wn * 64 + nf2 * 16 + lg * 4;
      float4 b24 = *(const float4*)(b2 + f0);
      float h0 = fmaxf(acc2[nf2][0] + b24.x, 0.f);
      float h1v = fmaxf(acc2[nf2][1] + b24.y, 0.f);
      float h2v = fmaxf(acc2[nf2][2] + b24.z, 0.f);
      float h3v = fmaxf(acc2[nf2][3] + b24.w, 0.f);
      if (valid) {
        float4 o = make_float4(h0, h1v, h2v, h3v);
        *(float4*)(out + (size_t)m * 128 + f0) = o;
      } else { h0 = h1v = h2v = h3v = 0.f; }
      hs[nf2][0] = h0; hs[nf2][1] = h1v; hs[nf2][2] = h2v; hs[nf2][3] = h3v;
      hq[nf2][0] = h0 * h0; hq[nf2][1] = h1v * h1v;
      hq[nf2][2] = h2v * h2v; hq[nf2][3] = h3v * h3v;
    }
    #pragma unroll
    for (int o = 1; o <= 8; o <<= 1)
      #pragma unroll
      for (int nf2 = 0; nf2 < 4; ++nf2)
        #pragma unroll
        for (int r = 0; r < 4; ++r) {
          hs[nf2][r] += __shfl_xor(hs[nf2][r], o);
          hq[nf2][r] += __shfl_xor(hq[nf2][r], o);
        }
    if (l15 == 0) {
      #pragma unroll
      for (int nf2 = 0; nf2 < 4; ++nf2) {
        int f0 = wn * 64 + nf2 * 16 + lg * 4;
        #pragma unroll
        for (int r = 0; r < 4; ++r) {
          atomicAdd(&bns[f0 + r], hs[nf2][r]);
          atomicAdd(&bnq[f0 + r], hq[nf2][r]);
        }
      }
    }
  }
  __syncthreads();
  if (tid < 128) {
    pbn[(size_t)blockIdx.x * 128 + tid] = bns[tid];
    pbq[(size_t)blockIdx.x * 128 + tid] = bnq[tid];
  }
}

// ---------------------------------------------------------------- BN stats: reduce per-block partials (one block per feature)
__global__ __launch_bounds__(256) void k_bnstats2(const float* __restrict__ pbn,
    const float* __restrict__ pbq, float* __restrict__ mean,
    float* __restrict__ istd) {
  int f = blockIdx.x;
  float s = 0.f, q = 0.f;
  for (int b = threadIdx.x; b < MGRID; b += 256) {
    s += pbn[(size_t)b * 128 + f];
    q += pbq[(size_t)b * 128 + f];
  }
  #pragma unroll
  for (int o = 32; o; o >>= 1) { s += __shfl_xor(s, o); q += __shfl_xor(q, o); }
  __shared__ float ss[4], sq[4];
  int wid = threadIdx.x >> 6, lane = threadIdx.x & 63;
  if (lane == 0) { ss[wid] = s; sq[wid] = q; }
  __syncthreads();
  if (threadIdx.x == 0) {
    float S = ss[0] + ss[1] + ss[2] + ss[3];
    float Q = sq[0] + sq[1] + sq[2] + sq[3];
    float mu = S / (float)NN;
    float var = fmaxf(Q / (float)NN - mu * mu, 0.f);
    mean[f] = mu;
    istd[f] = 1.f / sqrtf(var + 1e-5f);
  }
}

__global__ __launch_bounds__(256) void k_bnorm(float* __restrict__ out,
    const float* __restrict__ mean, const float* __restrict__ istd,
    const float* __restrict__ gamma, const float* __restrict__ beta) {
  int idx = blockIdx.x * 256 + threadIdx.x;
  float4* p = (float4*)out;
  float4 v = p[idx];
  int f = (idx & 31) << 2;
  v.x = gamma[f + 0] * (v.x - mean[f + 0]) * istd[f + 0] + beta[f + 0];
  v.y = gamma[f + 1] * (v.y - mean[f + 1]) * istd[f + 1] + beta[f + 1];
  v.z = gamma[f + 2] * (v.z - mean[f + 2]) * istd[f + 2] + beta[f + 2];
  v.w = gamma[f + 3] * (v.w - mean[f + 3]) * istd[f + 3] + beta[f + 3];
  p[idx] = v;
}

// ----------------------------------------------------------------
extern "C" void kernel_launch(void* const* d_in, const int* in_sizes, int n_in,
                              void* d_out, int out_size, void* d_ws, size_t ws_size,
                              hipStream_t stream) {
  (void)in_sizes; (void)n_in; (void)out_size; (void)ws_size;
  const float* nf    = (const float*)d_in[0];
  const int*   src   = (const int*)d_in[1];
  const int*   dst   = (const int*)d_in[2];
  const float* wed   = (const float*)d_in[3];
  const float* wes   = (const float*)d_in[4];
  const float* be    = (const float*)d_in[5];
  const float* wp    = (const float*)d_in[6];
  const float* bp    = (const float*)d_in[7];
  const float* w1    = (const float*)d_in[8];
  const float* b1    = (const float*)d_in[9];
  const float* w2    = (const float*)d_in[10];
  const float* b2    = (const float*)d_in[11];
  const float* gamma = (const float*)d_in[12];
  const float* beta  = (const float*)d_in[13];
  float* out = (float*)d_out;
  char* ws = (char*)d_ws;

  unsigned char*  hvb  = (unsigned char*)(ws + HVB_OFF);
  unsigned short* ctxb = (unsigned short*)(ws + CTXB_OFF);
  unsigned*       bin  = (unsigned*)(ws + BIN_OFF);
  unsigned short* srcs = (unsigned short*)(ws + SRCS_OFF);
  float* ld    = (float*)(ws + LD_OFF);
  float* ls    = (float*)(ws + LS_OFF);
  int*   start = (int*)(ws + START_OFF);
  int*   cntn  = (int*)(ws + CNTN_OFF);
  unsigned short* w1t = (unsigned short*)(ws + W1T_OFF);
  unsigned short* w2t = (unsigned short*)(ws + W2T_OFF);
  unsigned short* wpt = (unsigned short*)(ws + WPT_OFF);
  int*   bkc   = (int*)(ws + BKC_OFF);
  float* mean  = (float*)(ws + MEAN_OFF);
  float* istd  = (float*)(ws + ISTD_OFF);
  float* pbn   = (float*)(ws + PBN_OFF);
  float* pbq   = (float*)(ws + PBQ_OFF);

  hipMemsetAsync(ws + ZERO_OFF, 0, ZERO_LEN, stream);

  k_prep_w<<<256, 256, 0, stream>>>(w1, w2, wp, w1t, w2t, wpt);
  k_bin<<<(EE + BTILE - 1) / BTILE, 256, 0, stream>>>(src, dst, bkc, bin);
  k_hv2<<<(NN + 63) / 64, 256, 0, stream>>>(nf, wpt, bp, wed, wes, ld, ls, hvb);
  k_bsort<<<NB, 256, 0, stream>>>(bin, bkc, srcs, start, cntn);
  k_agg<<<12500, 256, 0, stream>>>(hvb, ld, ls, be, start, cntn, srcs, ctxb);
  k_mlp2<<<MGRID, 256, 0, stream>>>(ctxb, nf, w1t, b1, w2t, b2, out, pbn, pbq);
  k_bnstats2<<<128, 256, 0, stream>>>(pbn, pbq, mean, istd);
  k_bnorm<<<(NN * DD / 4) / 256, 256, 0, stream>>>(out, mean, istd, gamma, beta);
}